// Round 4
// baseline (76.672 us; speedup 1.0000x reference)
//
#include <hip/hip_runtime.h>
#include <hip/hip_bf16.h>

// out[b,w] = relu(sqrt(max(||x_b||^2 + ||w_w||^2 - 2*x_b.w_w, 0)) / sqrt(512))
// M=8192, N=4096, K=512.
// prep: w -> bf16 (wb) + wsq; xsq from fp32 x. GEMM: A read as fp32 directly
// (converted in-register, ds_write-staged, XOR-swizzled LDS), B staged via
// global_load_lds with pre-swizzled source; counted vmcnt, never drains.

typedef __bf16 bf16x8 __attribute__((ext_vector_type(8)));
typedef float f32x4 __attribute__((ext_vector_type(4)));

#define K_DIM 512
#define NT 8  // K_DIM / 64
#define INV_SCALE 0.04419417382415922f  // 1/22.627417

__device__ __forceinline__ ushort f2bf(float f) {
  __hip_bfloat16 h = __float2bfloat16(f);
  return __builtin_bit_cast(ushort, h);
}

// b < M: xsq[row] only. b >= M: w row -> bf16 + wsq[row].
__global__ __launch_bounds__(128) void prep_kernel(
    const float* __restrict__ x, const float* __restrict__ w,
    ushort* __restrict__ wb, float* __restrict__ xsq, float* __restrict__ wsq,
    int M) {
  int b = blockIdx.x;
  int t = threadIdx.x;
  const float* src; float* sq; int row; bool isW = b >= M;
  if (isW) { row = b - M; src = w; sq = wsq; }
  else     { row = b;     src = x; sq = xsq; }
  float4 v = reinterpret_cast<const float4*>(src + (size_t)row * K_DIM)[t];
  if (isW) {
    ushort4 p; p.x = f2bf(v.x); p.y = f2bf(v.y); p.z = f2bf(v.z); p.w = f2bf(v.w);
    reinterpret_cast<ushort4*>(wb + (size_t)row * K_DIM)[t] = p;
  }
  float s = v.x * v.x + v.y * v.y + v.z * v.z + v.w * v.w;
#pragma unroll
  for (int o = 32; o > 0; o >>= 1) s += __shfl_down(s, o, 64);
  __shared__ float red[2];
  if ((t & 63) == 0) red[t >> 6] = s;
  __syncthreads();
  if (t == 0) sq[row] = red[0] + red[1];
}

// 128x128 tile, BK=64, 4 waves (2x2). LDS: A 16 KB (single buf, swizzled) +
// B 2x16 KB (double buf, gll w/ pre-swizzled source). LDS(row,ch) holds
// global (row, ch ^ (row&7)); reads XOR the same way -> 2-way conflicts (free).
__global__ __launch_bounds__(256, 2) void gemm_dist_kernel(
    const float* __restrict__ x, const ushort* __restrict__ wb,
    const float* __restrict__ xsq, const float* __restrict__ wsq,
    float* __restrict__ out, int M, int N) {
  __shared__ ushort Asm[128 * 64];     // 16 KB
  __shared__ ushort Bsm[2][128 * 64];  // 32 KB

  const int ntN = N >> 7;                 // 32
  const int nwg = gridDim.x;              // 2048, % 8 == 0
  const int bid = blockIdx.x;
  const int swz = (bid & 7) * (nwg >> 3) + (bid >> 3);
  const int tR = swz / ntN, tC = swz - tR * ntN;
  const int rowA0 = tR << 7, rowB0 = tC << 7;

  const int tid = threadIdx.x;
  const int wid = tid >> 6, lane = tid & 63;
  const int wr = wid >> 1, wc = wid & 1;
  const int l15 = lane & 15, l4 = lane >> 4;
  const int sr8 = lane >> 3;   // row within 8-row stripe (= row & 7)
  const int sch = lane & 7;    // 8-float chunk within 64-col tile

  // A global: row rowA0 + wid*32 + c*8 + sr8, col t*64 + sch*8 (fp32).
  const float* xA = x + (size_t)(rowA0 + (wid << 5) + sr8) * K_DIM + (sch << 3);
  // B global (pre-swizzled source: fetch chunk sch^sr8 so linear gll dest
  // leaves LDS holding (row, ch) = global(row, ch^(row&7))):
  const ushort* wB = wb + (size_t)(rowB0 + (wid << 5) + sr8) * K_DIM + ((sch ^ sr8) << 3);

  f32x4 acc[4][4] = {};
  float4 aq[4][2];  // A prefetch regs: 32 floats

#define AISS(t) do {                                                           \
    _Pragma("unroll")                                                          \
    for (int c = 0; c < 4; ++c) {                                              \
      _Pragma("unroll")                                                        \
      for (int h = 0; h < 2; ++h)                                              \
        aq[c][h] = *reinterpret_cast<const float4*>(                           \
            xA + (size_t)(c * 8) * K_DIM + (t) * 64 + h * 4);                  \
    } } while (0)

#define BISS(t) do {                                                           \
    _Pragma("unroll")                                                          \
    for (int c = 0; c < 4; ++c)                                                \
      __builtin_amdgcn_global_load_lds(                                        \
          (const __attribute__((address_space(1))) void*)                      \
              (wB + (size_t)(c * 8) * K_DIM + (t) * 64),                       \
          (__attribute__((address_space(3))) void*)                            \
              (&Bsm[(t) & 1][((wid << 5) + (c << 3)) << 6]), 16, 0, 0);        \
  } while (0)

  // cvt aq -> bf16, ds_write at chunk (sch ^ sr8) of row wid*32+c*8+sr8.
#define ACVT() do {                                                            \
    _Pragma("unroll")                                                          \
    for (int c = 0; c < 4; ++c) {                                              \
      bf16x8 pk;                                                               \
      pk[0] = (__bf16)aq[c][0].x; pk[1] = (__bf16)aq[c][0].y;                  \
      pk[2] = (__bf16)aq[c][0].z; pk[3] = (__bf16)aq[c][0].w;                  \
      pk[4] = (__bf16)aq[c][1].x; pk[5] = (__bf16)aq[c][1].y;                  \
      pk[6] = (__bf16)aq[c][1].z; pk[7] = (__bf16)aq[c][1].w;                  \
      *reinterpret_cast<bf16x8*>(                                              \
          &Asm[(((wid << 5) + (c << 3) + sr8) << 6) + ((sch ^ sr8) << 3)]) = pk; \
    } } while (0)

  // Prologue: A0 regs + B0 gll; A0 landed (vmcnt(4): B0's 4 stay); cvt+write;
  // issue A1+B1; B0 landed (vmcnt(12): A1(8)+B1(4) stay); publish.
  AISS(0); BISS(0);
  asm volatile("s_waitcnt vmcnt(4)" : : : "memory");
  __builtin_amdgcn_sched_barrier(0);
  ACVT();
  AISS(1); BISS(1);
  asm volatile("s_waitcnt vmcnt(12)" : : : "memory");
  asm volatile("s_waitcnt lgkmcnt(0)" : : : "memory");
  asm volatile("s_barrier" : : : "memory");

  const int axorA = l15 & 7;
#pragma unroll
  for (int t = 0; t < NT; ++t) {
    // ---- compute tile t ----
#pragma unroll
    for (int kk = 0; kk < 2; ++kk) {
      const int ch = ((kk << 2) + l4);
      bf16x8 af[4], bg[4];
#pragma unroll
      for (int i = 0; i < 4; ++i)
        af[i] = *reinterpret_cast<const bf16x8*>(
            &Asm[(((wr << 6) + (i << 4) + l15) << 6) + ((ch ^ axorA) << 3)]);
#pragma unroll
      for (int j = 0; j < 4; ++j)
        bg[j] = *reinterpret_cast<const bf16x8*>(
            &Bsm[t & 1][(((wc << 6) + (j << 4) + l15) << 6) + ((ch ^ axorA) << 3)]);
      __builtin_amdgcn_s_setprio(1);
#pragma unroll
      for (int i = 0; i < 4; ++i)
#pragma unroll
        for (int j = 0; j < 4; ++j)
          acc[i][j] = __builtin_amdgcn_mfma_f32_16x16x32_bf16(af[i], bg[j], acc[i][j], 0, 0, 0);
      __builtin_amdgcn_s_setprio(0);
    }
    if (t == NT - 1) break;  // no phase 2 on last tile
    asm volatile("s_barrier" : : : "memory");  // #1: A & Bsm[t&1] free
    // in flight: A(t+1) 8 (oldest) + B(t+1) 4
    asm volatile("s_waitcnt vmcnt(4)" : : : "memory");
    __builtin_amdgcn_sched_barrier(0);
    ACVT();                                    // stage A(t+1)
    if (t + 2 < NT) {
      AISS(t + 2);
      BISS(t + 2);                             // -> Bsm[t&1], freed at #1
      asm volatile("s_waitcnt vmcnt(12)" : : : "memory");  // B(t+1) landed
    } else {
      asm volatile("s_waitcnt vmcnt(0)" : : : "memory");
    }
    asm volatile("s_waitcnt lgkmcnt(0)" : : : "memory");
    asm volatile("s_barrier" : : : "memory");  // #2: publish t+1
  }
#undef AISS
#undef BISS
#undef ACVT

  // Epilogue. C/D mapping: col = lane&15, row = (lane>>4)*4 + reg.
  const int rBase = rowA0 + (wr << 6) + (l4 << 2);
  const int cBase = rowB0 + (wc << 6) + l15;
  float wq[4];
#pragma unroll
  for (int j = 0; j < 4; ++j) wq[j] = wsq[cBase + (j << 4)];

#pragma unroll
  for (int i = 0; i < 4; ++i)
#pragma unroll
    for (int r = 0; r < 4; ++r) {
      const int row = rBase + (i << 4) + r;
      const float xq = xsq[row];
      const size_t ro = (size_t)row * (size_t)N;
#pragma unroll
      for (int j = 0; j < 4; ++j) {
        float v = xq + wq[j] - 2.0f * acc[i][j][r];
        __builtin_nontemporal_store(sqrtf(fmaxf(v, 0.0f)) * INV_SCALE,
                                    &out[ro + cBase + (j << 4)]);
      }
    }
}

extern "C" void kernel_launch(void* const* d_in, const int* in_sizes, int n_in,
                              void* d_out, int out_size, void* d_ws, size_t ws_size,
                              hipStream_t stream) {
  const float* x = (const float*)d_in[0];   // (M, 512) fp32
  const float* w = (const float*)d_in[1];   // (N, 512) fp32
  const int M = in_sizes[0] / K_DIM;        // 8192
  const int N = in_sizes[1] / K_DIM;        // 4096
  float* out = (float*)d_out;

  char* ws = (char*)d_ws;
  ushort* wb = (ushort*)ws;                               // N*K bf16 = 4 MB
  float* xsq = (float*)(ws + (size_t)N * K_DIM * 2);
  float* wsq = xsq + M;

  prep_kernel<<<M + N, 128, 0, stream>>>(x, w, wb, xsq, wsq, M);

  dim3 grid((M >> 7) * (N >> 7));  // 64 * 32 = 2048
  gemm_dist_kernel<<<grid, 256, 0, stream>>>(x, wb, xsq, wsq, out, M, N);
}